// Round 7
// baseline (108.199 us; speedup 1.0000x reference)
//
#include <hip/hip_runtime.h>

typedef _Float16 f16x8 __attribute__((ext_vector_type(8)));
typedef unsigned short u16x8 __attribute__((ext_vector_type(8)));
typedef float f32x4 __attribute__((ext_vector_type(4)));

#define NS 1024
#define NQ 1024
#define DD 128
#define NWAY 8
#define SCHUNK 128
#define QPER 8

// 16-lane (row) sum via DPP row_shr — VALU pipe, no LDS.
// Lane with (lane&15)==15 ends with the sum of its 16-lane row.
__device__ __forceinline__ float rowsum16(float v) {
    int t;
    t = __builtin_amdgcn_update_dpp(0, __float_as_int(v), 0x111, 0xF, 0xF, true);
    v += __int_as_float(t);
    t = __builtin_amdgcn_update_dpp(0, __float_as_int(v), 0x112, 0xF, 0xF, true);
    v += __int_as_float(t);
    t = __builtin_amdgcn_update_dpp(0, __float_as_int(v), 0x114, 0xF, 0xF, true);
    v += __int_as_float(t);
    t = __builtin_amdgcn_update_dpp(0, __float_as_int(v), 0x118, 0xF, 0xF, true);
    v += __int_as_float(t);
    return v;
}

// Main kernel: 128 supports x 8 queries per block.
// sim(q,s) = relu(|q-s| @ W1^T + b1) @ W2, bucketed by class.
// b2 dropped (uniform logit shift; log_softmax-invariant).
//
// Register-pressure history: bfrag-in-registers demanded ~190 regs;
// launch_bounds (256,3) [R3] and (256,4) [R5] then spilled 30-100 MB of
// scratch HBM traffic per dispatch, (256,2) [R4] was clean but latency-
// bound at 2 waves/SIMD (MfmaUtil 15%, VALUBusy 36%). Fix here: W1
// B-fragments are IDENTICAL across the block's 4 waves -> stage them in
// LDS once (16 KB), read per k-step via conflict-free ds_read_b128.
// That cuts per-wave demand to ~120 regs so (256,3) fits spill-free.
__global__ __launch_bounds__(256, 3) void siamese_main(
    const float* __restrict__ support_x,
    const int* __restrict__ support_y,
    const float* __restrict__ query_x,
    const float* __restrict__ W1,
    const float* __restrict__ b1,
    const float* __restrict__ W2,
    float* __restrict__ part)   // [8 sblk][NQ][NWAY]
{
    __shared__ _Float16 qtile[QPER][DD];       // 2 KB
    __shared__ _Float16 w1lds[16][64][8];      // 16 KB: [j*4+k][lane][e]
    __shared__ float clsbuf[QPER][NWAY];       // 256 B

    const int t = threadIdx.x;
    const int wave = t >> 6;
    const int lane = t & 63;
    const int c = lane & 15;     // MFMA m / n index
    const int quad = lane >> 4;  // MFMA k-group / row-group

    const int sblk = blockIdx.x & 7;
    const int qblk = blockIdx.x >> 3;
    const int s0 = sblk * SCHUNK;
    const int q0 = qblk * QPER;

    // ---- cooperative: W1 fragments -> LDS ----
    // fragment (j,k), lane l holds W1[h=j*16+(l&15)][d=k*32+(l>>4)*8 +0..8)
#pragma unroll
    for (int i = 0; i < 4; ++i) {
        const int jk = wave + i * 4;
        const int h = (jk >> 2) * 16 + (lane & 15);
        const int d = (jk & 3) * 32 + (lane >> 4) * 8;
        const float* wp = W1 + h * DD + d;
        float4 v0 = *(const float4*)(wp);
        float4 v1 = *(const float4*)(wp + 4);
        f16x8 s;
        s[0] = (_Float16)v0.x; s[1] = (_Float16)v0.y;
        s[2] = (_Float16)v0.z; s[3] = (_Float16)v0.w;
        s[4] = (_Float16)v1.x; s[5] = (_Float16)v1.y;
        s[6] = (_Float16)v1.z; s[7] = (_Float16)v1.w;
        *(f16x8*)&w1lds[jk][lane][0] = s;
    }

    // ---- one-time: support A-fragments in registers ----
    // sup[ii][k]: lane (quad,c) holds support row (s0 + (2*wave+ii)*16 + c),
    // d = k*32 + quad*8 + [0,8)   (A[m=lane&15][k=quad*8+e])
    f16x8 sup[2][4];
#pragma unroll
    for (int ii = 0; ii < 2; ++ii) {
        const int st = 2 * wave + ii;
        const float* sp = support_x + (size_t)(s0 + st * 16 + c) * DD + quad * 8;
#pragma unroll
        for (int k = 0; k < 4; ++k) {
            float4 v0 = *(const float4*)(sp + k * 32);
            float4 v1 = *(const float4*)(sp + k * 32 + 4);
            f16x8 s;
            s[0] = (_Float16)v0.x; s[1] = (_Float16)v0.y;
            s[2] = (_Float16)v0.z; s[3] = (_Float16)v0.w;
            s[4] = (_Float16)v1.x; s[5] = (_Float16)v1.y;
            s[6] = (_Float16)v1.z; s[7] = (_Float16)v1.w;
            sup[ii][k] = s;
        }
    }

    // ---- one-time: b1/W2 per-lane (h = j*16 + c), labels per-lane ----
    float b1h[4], w2h[4];
#pragma unroll
    for (int j = 0; j < 4; ++j) {
        b1h[j] = b1[j * 16 + c];
        w2h[j] = W2[j * 16 + c];
    }

    int lbl[2][4];
#pragma unroll
    for (int ii = 0; ii < 2; ++ii)
#pragma unroll
        for (int r = 0; r < 4; ++r)
            lbl[ii][r] = support_y[s0 + (2 * wave + ii) * 16 + quad * 4 + r];

    // ---- stage QPER query rows (f16) + zero class buckets ----
    {
        const int q = t >> 5;
        const int dd = (t & 31) * 4;
        float4 v = *(const float4*)(query_x + (size_t)(q0 + q) * DD + dd);
        _Float16* dst = &qtile[q][dd];
        dst[0] = (_Float16)v.x; dst[1] = (_Float16)v.y;
        dst[2] = (_Float16)v.z; dst[3] = (_Float16)v.w;
    }
    if (t < QPER * NWAY) clsbuf[t >> 3][t & 7] = 0.f;
    __syncthreads();

    for (int qq = 0; qq < QPER; ++qq) {
        // accumulators pre-seeded with b1 (C col = c -> h = j*16+c)
        f32x4 acc[2][4];
#pragma unroll
        for (int ii = 0; ii < 2; ++ii)
#pragma unroll
            for (int j = 0; j < 4; ++j)
                acc[ii][j] = (f32x4){b1h[j], b1h[j], b1h[j], b1h[j]};

#pragma unroll
        for (int k = 0; k < 4; ++k) {
            // quad-uniform broadcast read of the query slice for this k
            f16x8 qf = *(const f16x8*)&qtile[qq][k * 32 + quad * 8];
            // W1 B-fragments for this k (conflict-free stride-1 reads)
            f16x8 bf[4];
#pragma unroll
            for (int j = 0; j < 4; ++j)
                bf[j] = *(const f16x8*)&w1lds[j * 4 + k][lane][0];
#pragma unroll
            for (int ii = 0; ii < 2; ++ii) {
                f16x8 dv = sup[ii][k] - qf;
                union { f16x8 f; u16x8 u; } cv;
                cv.f = dv;
                cv.u = cv.u & (unsigned short)0x7fffu;  // |diff|
#pragma unroll
                for (int j = 0; j < 4; ++j)
                    acc[ii][j] = __builtin_amdgcn_mfma_f32_16x16x32_f16(
                        cv.f, bf[j], acc[ii][j], 0, 0, 0);
            }
        }

        // epilogue: sim(s) = sum_h relu(H)*W2[h]; LDS-atomic class bucket
#pragma unroll
        for (int ii = 0; ii < 2; ++ii) {
#pragma unroll
            for (int r = 0; r < 4; ++r) {
                float val = 0.f;
#pragma unroll
                for (int j = 0; j < 4; ++j)
                    val = fmaf(fmaxf(acc[ii][j][r], 0.f), w2h[j], val);
                float v = rowsum16(val);
                if (c == 15) atomicAdd(&clsbuf[qq][lbl[ii][r]], v);
            }
        }
    }
    __syncthreads();

    // one coalesced 64-float store: part[sblk][q0..q0+7][0..7]
    if (t < QPER * NWAY)
        part[(size_t)sblk * (NQ * NWAY) + q0 * NWAY + t] = clsbuf[t >> 3][t & 7];
}

// Finalize: sum 8 partials, counts, per-class mean, log_softmax.
// Grid 8 x 128 threads (one thread per query).
__global__ void siamese_finalize(
    const int* __restrict__ support_y,
    const float* __restrict__ part,
    float* __restrict__ out)
{
    __shared__ float cnt[NWAY];
    const int t = threadIdx.x;
    if (t < NWAY) cnt[t] = 0.f;
    __syncthreads();
#pragma unroll
    for (int i = 0; i < NS / 128; ++i)
        atomicAdd(&cnt[support_y[t * (NS / 128) + i]], 1.0f);
    __syncthreads();

    const int q = blockIdx.x * 128 + t;
    float lg[NWAY];
    float mx = -1e30f;
#pragma unroll
    for (int k = 0; k < NWAY; ++k) {
        float s = 0.f;
#pragma unroll
        for (int sb = 0; sb < 8; ++sb)
            s += part[(size_t)sb * (NQ * NWAY) + q * NWAY + k];
        lg[k] = s / cnt[k];
        mx = fmaxf(mx, lg[k]);
    }
    float ss = 0.f;
#pragma unroll
    for (int k = 0; k < NWAY; ++k) ss += expf(lg[k] - mx);
    const float lse = mx + logf(ss);
#pragma unroll
    for (int k = 0; k < NWAY; ++k) out[q * NWAY + k] = lg[k] - lse;
}

extern "C" void kernel_launch(void* const* d_in, const int* in_sizes, int n_in,
                              void* d_out, int out_size, void* d_ws, size_t ws_size,
                              hipStream_t stream) {
    const float* support_x = (const float*)d_in[0];
    const int* support_y   = (const int*)d_in[1];
    const float* query_x   = (const float*)d_in[2];
    // d_in[3] = n_way (scalar, fixed at 8) — unused
    const float* W1 = (const float*)d_in[4];
    const float* b1 = (const float*)d_in[5];
    const float* W2 = (const float*)d_in[6];
    // d_in[7] = b2 — dropped (uniform logit shift, log_softmax-invariant)

    float* part = (float*)d_ws;  // [8][NQ][NWAY] fp32 partials, 256 KB
    // every slot is written unconditionally by siamese_main — no memset needed

    siamese_main<<<dim3((NS / SCHUNK) * (NQ / QPER)), dim3(256), 0, stream>>>(
        support_x, support_y, query_x, W1, b1, W2, part);
    siamese_finalize<<<dim3(NQ / 128), dim3(128), 0, stream>>>(
        support_y, part, (float*)d_out);
}

// Round 8
// 94.076 us; speedup vs baseline: 1.1501x; 1.1501x over previous
//
#include <hip/hip_runtime.h>

typedef _Float16 f16x4 __attribute__((ext_vector_type(4)));
typedef _Float16 f16x8 __attribute__((ext_vector_type(8)));
typedef unsigned short u16x8 __attribute__((ext_vector_type(8)));
typedef float f32x4 __attribute__((ext_vector_type(4)));

#define NS 1024
#define NQ 1024
#define DD 128
#define NWAY 8
#define SCHUNK 128
#define QPER 16

// d_ws layout (bytes):
//   0        part  [8][NQ][NWAY] f32   (256 KB)
//   0x40000  sup16 [NS][DD] f16        (256 KB)
//   0x80000  q16   [NQ][DD] f16        (256 KB)
//   0xC0000  w1f   [16 frag][64 lane][8] f16  (16 KB, fragment-ordered)

// Prep: one-time f32->f16 conversion of support/query/W1 (W1 directly in
// MFMA fragment order). Removes all per-block cvt VALU + float4 temp
// pressure from the main kernel (the driver of every spill: R3/R5/R7).
__global__ void siamese_prep(const float* __restrict__ sx,
                             const float* __restrict__ qx,
                             const float* __restrict__ W1,
                             _Float16* __restrict__ sup16,
                             _Float16* __restrict__ q16,
                             _Float16* __restrict__ w1f)
{
    const int tid = blockIdx.x * 256 + threadIdx.x;
    if (blockIdx.x < 128) {                       // support: 32768 float4
        float4 v = ((const float4*)sx)[tid];
        f16x4 h; h[0] = (_Float16)v.x; h[1] = (_Float16)v.y;
        h[2] = (_Float16)v.z; h[3] = (_Float16)v.w;
        ((f16x4*)sup16)[tid] = h;
    } else if (blockIdx.x < 256) {                // query: 32768 float4
        const int i = tid - 32768;
        float4 v = ((const float4*)qx)[i];
        f16x4 h; h[0] = (_Float16)v.x; h[1] = (_Float16)v.y;
        h[2] = (_Float16)v.z; h[3] = (_Float16)v.w;
        ((f16x4*)q16)[i] = h;
    } else {                                      // W1 frags: 16*64 = 1024
        const int i = tid - 65536;
        const int jk = i >> 6, l = i & 63;
        const int h = (jk >> 2) * 16 + (l & 15);
        const int d = (jk & 3) * 32 + (l >> 4) * 8;
        const float* wp = W1 + h * DD + d;
        float4 v0 = *(const float4*)(wp);
        float4 v1 = *(const float4*)(wp + 4);
        f16x8 s;
        s[0] = (_Float16)v0.x; s[1] = (_Float16)v0.y;
        s[2] = (_Float16)v0.z; s[3] = (_Float16)v0.w;
        s[4] = (_Float16)v1.x; s[5] = (_Float16)v1.y;
        s[6] = (_Float16)v1.z; s[7] = (_Float16)v1.w;
        *(f16x8*)(w1f + (size_t)i * 8) = s;
    }
}

// Main: 128 supports x 16 queries per block, grid 512 = exactly 2
// blocks/CU at (256,2) -> one co-resident round, prologue paid once.
// sim(q,s) = relu(|q-s| @ W1^T + b1) @ W2, class-bucketed via LDS atomics.
// b2 dropped (uniform logit shift; log_softmax-invariant).
//
// MFMA operands SWAPPED vs R4: A = W1 fragment, B = diff fragment (the
// register layouts are bit-identical; only the intrinsic arg order flips).
// C then has s on the column index (col=lane&15) and h on the row index
// (h = j*16 + quad*4 + r), so the h-reduction is per-lane fma over own
// regs + 2 cross-quad shuffles — no 16-lane DPP chains.
//
// launch_bounds MUST stay (256,2): caps of 170/128 regs (R3/R5/R7) all
// produced 8-100 MB of scratch spill traffic. (256,2) is spill-free.
__global__ __launch_bounds__(256, 2) void siamese_main(
    const _Float16* __restrict__ sup16,
    const int* __restrict__ support_y,
    const _Float16* __restrict__ q16,
    const _Float16* __restrict__ w1f,
    const float* __restrict__ b1,
    const float* __restrict__ W2,
    float* __restrict__ part)   // [8 sblk][NQ][NWAY]
{
    __shared__ _Float16 qtile[QPER][DD];       // 4 KB
    __shared__ float clsbuf[QPER][NWAY];       // 512 B

    const int t = threadIdx.x;
    const int wave = t >> 6;
    const int lane = t & 63;
    const int c = lane & 15;     // MFMA n index -> support col
    const int quad = lane >> 4;  // MFMA k-group / C row-group

    const int sblk = blockIdx.x & 7;
    const int qblk = blockIdx.x >> 3;
    const int s0 = sblk * SCHUNK;
    const int q0 = qblk * QPER;

    // ---- one-time: support B-fragments (pure f16 16B loads) ----
    // sup[ii][k]: lane (quad,c) holds sup16[s0+(2*wave+ii)*16+c][k*32+quad*8 ..+8)
    f16x8 sup[2][4];
#pragma unroll
    for (int ii = 0; ii < 2; ++ii) {
        const _Float16* sp = sup16 + (size_t)(s0 + (2 * wave + ii) * 16 + c) * DD + quad * 8;
#pragma unroll
        for (int k = 0; k < 4; ++k)
            sup[ii][k] = *(const f16x8*)(sp + k * 32);
    }

    // ---- one-time: W1 A-fragments (fragment-ordered, 16B loads) ----
    f16x8 afrag[4][4];
#pragma unroll
    for (int j = 0; j < 4; ++j)
#pragma unroll
        for (int k = 0; k < 4; ++k)
            afrag[j][k] = *(const f16x8*)(w1f + (size_t)((j * 4 + k) * 64 + lane) * 8);

    // ---- one-time: b1/W2 rows for this lane (h = j*16 + quad*4 + r) ----
    f32x4 b1v[4], w2v[4];
#pragma unroll
    for (int j = 0; j < 4; ++j) {
        b1v[j] = *(const f32x4*)(b1 + j * 16 + quad * 4);
        w2v[j] = *(const f32x4*)(W2 + j * 16 + quad * 4);
    }

    // labels for this lane's support column
    int lbl[2];
#pragma unroll
    for (int ii = 0; ii < 2; ++ii)
        lbl[ii] = support_y[s0 + (2 * wave + ii) * 16 + c];

    // ---- stage QPER query rows (f16, direct 16B copies) ----
    {
        const int q = t >> 4;
        const int dd = (t & 15) * 8;
        *(f16x8*)&qtile[q][dd] = *(const f16x8*)(q16 + (size_t)(q0 + q) * DD + dd);
    }
    if (t < QPER * NWAY) clsbuf[t >> 3][t & 7] = 0.f;
    __syncthreads();

    for (int qq = 0; qq < QPER; ++qq) {
        // accumulators pre-seeded with b1 (row r -> h = j*16+quad*4+r)
        f32x4 acc[2][4];
#pragma unroll
        for (int ii = 0; ii < 2; ++ii)
#pragma unroll
            for (int j = 0; j < 4; ++j)
                acc[ii][j] = b1v[j];

#pragma unroll
        for (int k = 0; k < 4; ++k) {
            // quad-uniform broadcast read of the query slice for this k
            f16x8 qf = *(const f16x8*)&qtile[qq][k * 32 + quad * 8];
#pragma unroll
            for (int ii = 0; ii < 2; ++ii) {
                union { f16x8 f; u16x8 u; } cv;
                cv.f = sup[ii][k] - qf;
                cv.u = cv.u & (unsigned short)0x7fffu;  // |diff|
#pragma unroll
                for (int j = 0; j < 4; ++j)
                    acc[ii][j] = __builtin_amdgcn_mfma_f32_16x16x32_f16(
                        afrag[j][k], cv.f, acc[ii][j], 0, 0, 0);
            }
        }

        // epilogue: per-lane fma over own 16 h values, then cross-quad sum
#pragma unroll
        for (int ii = 0; ii < 2; ++ii) {
            float val = 0.f;
#pragma unroll
            for (int j = 0; j < 4; ++j)
#pragma unroll
                for (int r = 0; r < 4; ++r)
                    val = fmaf(fmaxf(acc[ii][j][r], 0.f), w2v[j][r], val);
            val += __shfl_xor(val, 16);
            val += __shfl_xor(val, 32);
            if (quad == 0) atomicAdd(&clsbuf[qq][lbl[ii]], val);
        }
    }
    __syncthreads();

    // one coalesced 128-float store: part[sblk][q0..q0+15][0..7]
    if (t < QPER * NWAY)
        part[(size_t)sblk * (NQ * NWAY) + q0 * NWAY + t] = clsbuf[t >> 3][t & 7];
}

// Finalize: sum 8 partials, counts, per-class mean, log_softmax.
// Grid 8 x 128 threads (one thread per query).
__global__ void siamese_finalize(
    const int* __restrict__ support_y,
    const float* __restrict__ part,
    float* __restrict__ out)
{
    __shared__ float cnt[NWAY];
    const int t = threadIdx.x;
    if (t < NWAY) cnt[t] = 0.f;
    __syncthreads();
#pragma unroll
    for (int i = 0; i < NS / 128; ++i)
        atomicAdd(&cnt[support_y[t * (NS / 128) + i]], 1.0f);
    __syncthreads();

    const int q = blockIdx.x * 128 + t;
    float lg[NWAY];
    float mx = -1e30f;
#pragma unroll
    for (int k = 0; k < NWAY; ++k) {
        float s = 0.f;
#pragma unroll
        for (int sb = 0; sb < 8; ++sb)
            s += part[(size_t)sb * (NQ * NWAY) + q * NWAY + k];
        lg[k] = s / cnt[k];
        mx = fmaxf(mx, lg[k]);
    }
    float ss = 0.f;
#pragma unroll
    for (int k = 0; k < NWAY; ++k) ss += expf(lg[k] - mx);
    const float lse = mx + logf(ss);
#pragma unroll
    for (int k = 0; k < NWAY; ++k) out[q * NWAY + k] = lg[k] - lse;
}

extern "C" void kernel_launch(void* const* d_in, const int* in_sizes, int n_in,
                              void* d_out, int out_size, void* d_ws, size_t ws_size,
                              hipStream_t stream) {
    const float* support_x = (const float*)d_in[0];
    const int* support_y   = (const int*)d_in[1];
    const float* query_x   = (const float*)d_in[2];
    // d_in[3] = n_way (scalar, fixed at 8) — unused
    const float* W1 = (const float*)d_in[4];
    const float* b1 = (const float*)d_in[5];
    const float* W2 = (const float*)d_in[6];
    // d_in[7] = b2 — dropped (uniform logit shift, log_softmax-invariant)

    char* ws = (char*)d_ws;
    float* part       = (float*)(ws);                 // 256 KB
    _Float16* sup16   = (_Float16*)(ws + 0x40000);    // 256 KB
    _Float16* q16     = (_Float16*)(ws + 0x80000);    // 256 KB
    _Float16* w1f     = (_Float16*)(ws + 0xC0000);    // 16 KB

    siamese_prep<<<dim3(260), dim3(256), 0, stream>>>(
        support_x, query_x, W1, sup16, q16, w1f);
    siamese_main<<<dim3(8 * (NQ / QPER)), dim3(256), 0, stream>>>(
        sup16, support_y, q16, w1f, b1, W2, part);
    siamese_finalize<<<dim3(NQ / 128), dim3(128), 0, stream>>>(
        support_y, part, (float*)d_out);
}